// Round 10
// baseline (2107.276 us; speedup 1.0000x reference)
//
#include <hip/hip_runtime.h>
#include <math.h>

#define BATCH 64
#define SEQ 300
#define DM 1024
#define DP 128
#define NH 4
#define NC 3862
#define MROWS (BATCH*SEQ)   // 19200
#define NSTK (6*DP)         // 768: [K | V | Q0..Q3]

#define BM 128
#define BN 128
#define BK 16

typedef double d4 __attribute__((ext_vector_type(4)));

// ---------------------------------------------------------------------------
// Kernel 1: fused QKV projection GEMM on the f64 MFMA pipe.
// Identical math/staging to the r9 PASS (swizzled, conflict-free); only
// occupancy raised: __launch_bounds__(256,4) -> 4 blocks/CU so resident
// blocks compute through each other's barrier vmcnt-drains.
// f64 MFMA layouts (HW-confirmed): A: i=lane&15, k=lane>>4;
// B: j=lane&15, k=lane>>4; D: row=(lane>>4)+4*reg, col=lane&15.
// ---------------------------------------------------------------------------
__global__ __launch_bounds__(256, 4) void proj_gemm_mfma(
    const float* __restrict__ X,
    const float* __restrict__ Wk, const float* __restrict__ bk,
    const float* __restrict__ Wv, const float* __restrict__ bv,
    const float* __restrict__ Wq, const float* __restrict__ bq,
    float* __restrict__ O)
{
    const int mtile = blockIdx.x;   // 0..149
    const int wsel  = blockIdx.y;   // 0..5 : K,V,Q0..Q3

    const float* Wbase; const float* bias;
    if (wsel == 0)      { Wbase = Wk; bias = bk; }
    else if (wsel == 1) { Wbase = Wv; bias = bv; }
    else                { Wbase = Wq + (size_t)(wsel - 2) * DP * DM;
                          bias  = bq + (wsel - 2) * DP; }

    // [row][k] tiles; slot s holds global granule (row=s>>2, kq=(s&3)^((row>>2)&3))
    __shared__ float As[2][BM * BK];
    __shared__ float Bs[2][BN * BK];

    const int tid  = threadIdx.x;
    const int lane = tid & 63;
    const int wave = tid >> 6;
    const int wm = wave >> 1, wn = wave & 1;   // 2x2 wave grid
    const int mbase = mtile * BM;

    const int r = lane & 15;   // A row / B col / D col within 16-tile
    const int g = lane >> 4;   // k-subindex (0..3) for A/B; D row base
    const int sw = (r >> 2) & 3;   // per-lane XOR swizzle key

    d4 acc[4][4];
    #pragma unroll
    for (int mt = 0; mt < 4; ++mt)
        #pragma unroll
        for (int nt = 0; nt < 4; ++nt)
            acc[mt][nt] = (d4)(0.0);

#define STAGE(bufi, k0)                                                        \
    do {                                                                       \
        _Pragma("unroll")                                                      \
        for (int j = 0; j < 2; ++j) {                                          \
            const int slotbase = wave * 128 + j * 64;   /* wave-uniform */     \
            const int slot = slotbase + lane;                                  \
            const int mrow = slot >> 2;                                        \
            const int kq4  = (((slot & 3) ^ ((mrow >> 2) & 3))) << 2;          \
            const float* srcA = &X[(size_t)(mbase + mrow) * DM + (k0) + kq4];  \
            __builtin_amdgcn_global_load_lds(                                  \
                (const __attribute__((address_space(1))) void*)srcA,           \
                (__attribute__((address_space(3))) void*)&As[bufi][slotbase * 4], \
                16, 0, 0);                                                     \
            const float* srcB = &Wbase[(size_t)mrow * DM + (k0) + kq4];        \
            __builtin_amdgcn_global_load_lds(                                  \
                (const __attribute__((address_space(1))) void*)srcB,           \
                (__attribute__((address_space(3))) void*)&Bs[bufi][slotbase * 4], \
                16, 0, 0);                                                     \
        }                                                                      \
    } while (0)

    STAGE(0, 0);
    __syncthreads();   // drains vmcnt -> buf0 ready

    int buf = 0;
    for (int t = 0; t < DM / BK; ++t) {
        if (t + 1 < DM / BK) {
            if (buf == 0) STAGE(1, (t + 1) * BK);
            else          STAGE(0, (t + 1) * BK);
        }
        #pragma unroll
        for (int kq = 0; kq < 4; ++kq) {
            const int kqs = ((kq ^ sw) << 2) + g;
            double a[4], b[4];
            #pragma unroll
            for (int mt = 0; mt < 4; ++mt)
                a[mt] = (double)As[buf][(wm * 64 + mt * 16 + r) * BK + kqs];
            #pragma unroll
            for (int nt = 0; nt < 4; ++nt)
                b[nt] = (double)Bs[buf][(wn * 64 + nt * 16 + r) * BK + kqs];
            #pragma unroll
            for (int mt = 0; mt < 4; ++mt)
                #pragma unroll
                for (int nt = 0; nt < 4; ++nt)
                    acc[mt][nt] = __builtin_amdgcn_mfma_f64_16x16x4f64(
                        a[mt], b[nt], acc[mt][nt], 0, 0, 0);
        }
        __syncthreads();
        buf ^= 1;
    }
#undef STAGE

    // epilogue: D[row = g + 4*i][col = r] per 16x16 tile (f64 reg-strided)
    #pragma unroll
    for (int nt = 0; nt < 4; ++nt) {
        const int col = wn * 64 + nt * 16 + r;
        const double bi = (double)bias[col];
        #pragma unroll
        for (int mt = 0; mt < 4; ++mt) {
            #pragma unroll
            for (int i = 0; i < 4; ++i) {
                const int row = wm * 64 + mt * 16 + g + 4 * i;
                O[(size_t)(mbase + row) * NSTK + wsel * DP + col] =
                    (float)(acc[mt][nt][i] + bi);
            }
        }
    }
}

// ---------------------------------------------------------------------------
// Kernel 2: merged attention + logits GEMV + LN stats, per (b,h).
// 512 threads. Scores: 16-lane groups (4-level shuffle). ws kept in LDS
// (no global roundtrip). All reduction math f64 (argmax safety).
// ---------------------------------------------------------------------------
__global__ __launch_bounds__(512) void attn_logits_kernel(
    const float* __restrict__ QKV,
    const float* __restrict__ Wc, const float* __restrict__ bc,
    float* __restrict__ scores_out,  // [B][S][H] f32
    float* __restrict__ attnw_out,   // [B][S][H] f32
    double* __restrict__ logits,     // [BH][NC] f64
    double* __restrict__ stats)      // [BH][2]  f64
{
    const int b = blockIdx.x >> 2;
    const int h = blockIdx.x & 3;
    const int bh = blockIdx.x;
    const int tid = threadIdx.x;
    const int wave = tid >> 6, lane = tid & 63;

    __shared__ double sc[SEQ];
    __shared__ double red[8];
    __shared__ double wacc[4][DP];
    __shared__ double wsLDS[DP];

    const double scale = 0.08838834764831843;  // 1/sqrt(128)
    const float* base = QKV + (size_t)b * SEQ * NSTK;

    // ---- Phase A: scores. One 16-lane group per s (8 dims/lane).
    {
        const int grp = tid >> 4;   // 0..31
        const int l16 = tid & 15;
        for (int s = grp; s < SEQ; s += 32) {
            const float* row = base + (size_t)s * NSTK;
            const float4 q0 = *reinterpret_cast<const float4*>(row + 256 + h * DP + l16 * 8);
            const float4 q1 = *reinterpret_cast<const float4*>(row + 256 + h * DP + l16 * 8 + 4);
            const float4 k0 = *reinterpret_cast<const float4*>(row + l16 * 8);
            const float4 k1 = *reinterpret_cast<const float4*>(row + l16 * 8 + 4);
            double p = (double)q0.x * (double)k0.x + (double)q0.y * (double)k0.y
                     + (double)q0.z * (double)k0.z + (double)q0.w * (double)k0.w
                     + (double)q1.x * (double)k1.x + (double)q1.y * (double)k1.y
                     + (double)q1.z * (double)k1.z + (double)q1.w * (double)k1.w;
            p += __shfl_xor(p, 1);
            p += __shfl_xor(p, 2);
            p += __shfl_xor(p, 4);
            p += __shfl_xor(p, 8);
            p *= scale;
            if (l16 == 0) {
                sc[s] = p;
                scores_out[((size_t)b * SEQ + s) * NH + h] = (float)p;
            }
        }
    }
    __syncthreads();

    // ---- Phase B: softmax over SEQ (f64)
    double mx = -1e300;
    for (int i = tid; i < SEQ; i += 512) mx = fmax(mx, sc[i]);
    #pragma unroll
    for (int o = 32; o; o >>= 1) mx = fmax(mx, __shfl_xor(mx, o));
    if (lane == 0) red[wave] = mx;
    __syncthreads();
    mx = red[0];
    #pragma unroll
    for (int w = 1; w < 8; ++w) mx = fmax(mx, red[w]);
    __syncthreads();

    double lsum = 0.0;
    for (int i = tid; i < SEQ; i += 512) {
        const double e = exp(sc[i] - mx);
        sc[i] = e;
        lsum += e;
    }
    #pragma unroll
    for (int o = 32; o; o >>= 1) lsum += __shfl_xor(lsum, o);
    if (lane == 0) red[wave] = lsum;
    __syncthreads();
    double tot = 0.0;
    #pragma unroll
    for (int w = 0; w < 8; ++w) tot += red[w];
    const double inv = 1.0 / tot;
    __syncthreads();
    for (int i = tid; i < SEQ; i += 512) {
        const double p = sc[i] * inv;
        sc[i] = p;
        attnw_out[((size_t)b * SEQ + i) * NH + h] = (float)p;
    }
    __syncthreads();

    // ---- Phase C: ws[p] = sum_s p_attn[s] * vals[s][p]; 4 s-partials
    {
        const int p_idx = tid & 127, qtr = tid >> 7;
        double acc = 0.0;
        for (int s = qtr; s < SEQ; s += 4)
            acc = fma(sc[s], (double)base[(size_t)s * NSTK + 128 + p_idx], acc);
        wacc[qtr][p_idx] = acc;
    }
    __syncthreads();
    if (tid < DP) {
        const double w = wacc[0][tid] + wacc[1][tid] + wacc[2][tid] + wacc[3][tid];
        wsLDS[tid] = fmax(w, 0.0);   // relu
    }
    __syncthreads();

    // ---- Phase D: logits GEMV + LN stats
    double vals[8];
    int cnt = 0;
    double psum = 0.0;
    for (int c = tid; c < NC; c += 512) {
        const float4* wr = reinterpret_cast<const float4*>(Wc + (size_t)c * DP);
        double acc = 0.0;
        #pragma unroll
        for (int k = 0; k < 32; ++k) {
            const float4 v = wr[k];
            acc = fma((double)v.x, wsLDS[4 * k + 0], acc);
            acc = fma((double)v.y, wsLDS[4 * k + 1], acc);
            acc = fma((double)v.z, wsLDS[4 * k + 2], acc);
            acc = fma((double)v.w, wsLDS[4 * k + 3], acc);
        }
        acc += (double)bc[c];
        logits[(size_t)bh * NC + c] = acc;
        vals[cnt++] = acc;
        psum += acc;
    }
    #pragma unroll
    for (int o = 32; o; o >>= 1) psum += __shfl_xor(psum, o);
    if (lane == 0) red[wave] = psum;
    __syncthreads();
    double msum = 0.0;
    #pragma unroll
    for (int w = 0; w < 8; ++w) msum += red[w];
    const double mean = msum / (double)NC;
    __syncthreads();

    double lss = 0.0;
    for (int i = 0; i < cnt; ++i) {
        const double d = vals[i] - mean;
        lss = fma(d, d, lss);
    }
    #pragma unroll
    for (int o = 32; o; o >>= 1) lss += __shfl_xor(lss, o);
    if (lane == 0) red[wave] = lss;
    __syncthreads();
    if (tid == 0) {
        double vsum = 0.0;
        #pragma unroll
        for (int w = 0; w < 8; ++w) vsum += red[w];
        stats[bh * 2 + 0] = mean;
        stats[bh * 2 + 1] = sqrt(vsum / (double)(NC - 1));
    }
}

// ---------------------------------------------------------------------------
// Kernel 3: LN + max/argmax over heads + sigmoid, f64 compare path.
// ---------------------------------------------------------------------------
__global__ __launch_bounds__(256) void finalize_kernel(
    const double* __restrict__ logits, const double* __restrict__ stats,
    const float* __restrict__ ln_a, const float* __restrict__ ln_b,
    float* __restrict__ vid_probs, float* __restrict__ attn_idc)
{
    const int c = blockIdx.x * 256 + threadIdx.x;
    const int b = blockIdx.y;
    if (c >= NC) return;
    const double a = (double)ln_a[c], bb = (double)ln_b[c];
    double best = -1e300;
    int bi = 0;
    #pragma unroll
    for (int h = 0; h < NH; ++h) {
        const int bh = b * NH + h;
        const double x = logits[(size_t)bh * NC + c];
        const double ln = a * (x - stats[bh * 2]) / (stats[bh * 2 + 1] + 1e-6) + bb;
        if (ln > best) { best = ln; bi = h; }
    }
    vid_probs[(size_t)b * NC + c] = (float)(1.0 / (1.0 + exp(-best)));
    attn_idc[(size_t)b * NC + c] = (float)bi;
}

// ---------------------------------------------------------------------------
// Kernel 4: conv regularizer loss (Wc, bc only), f64. One block, 1024 thr.
// ---------------------------------------------------------------------------
__global__ __launch_bounds__(1024) void convloss_kernel(
    const float* __restrict__ Wc, const float* __restrict__ bc,
    float* __restrict__ out)
{
    __shared__ double t[NC];
    __shared__ double red[16];
    const int tid = threadIdx.x;
    const int wave = tid >> 6, lane = tid & 63;

    double lmax = -1e300;
    for (int c = tid; c < NC; c += 1024) {
        const float4* wr = reinterpret_cast<const float4*>(Wc + (size_t)c * DP);
        double acc = 0.0;
        #pragma unroll
        for (int k = 0; k < 32; ++k) {
            const float4 v = wr[k];
            acc += (double)v.x + (double)v.y + (double)v.z + (double)v.w;
        }
        acc += (double)bc[c];
        t[c] = acc;
        lmax = fmax(lmax, acc);
    }
    #pragma unroll
    for (int o = 32; o; o >>= 1) lmax = fmax(lmax, __shfl_xor(lmax, o));
    if (lane == 0) red[wave] = lmax;
    __syncthreads();
    double mx = red[0];
    #pragma unroll
    for (int w = 1; w < 16; ++w) mx = fmax(mx, red[w]);
    __syncthreads();

    double lsum = 0.0;
    for (int c = tid; c < NC; c += 1024) {
        const double e = exp(t[c] - mx);
        t[c] = e;
        lsum += e;
    }
    #pragma unroll
    for (int o = 32; o; o >>= 1) lsum += __shfl_xor(lsum, o);
    if (lane == 0) red[wave] = lsum;
    __syncthreads();
    double tot = 0.0;
    #pragma unroll
    for (int w = 0; w < 16; ++w) tot += red[w];
    const double inv = 1.0 / tot;
    __syncthreads();

    double psum = 0.0;
    for (int c = tid; c < NC; c += 1024) {
        const double p = t[c] * inv;
        t[c] = p;
        psum += p;
    }
    #pragma unroll
    for (int o = 32; o; o >>= 1) psum += __shfl_xor(psum, o);
    if (lane == 0) red[wave] = psum;
    __syncthreads();
    double msum = 0.0;
    #pragma unroll
    for (int w = 0; w < 16; ++w) msum += red[w];
    const double mean = msum / (double)NC;
    __syncthreads();

    double lss = 0.0;
    for (int c = tid; c < NC; c += 1024) {
        const double d = t[c] - mean;
        lss = fma(d, d, lss);
    }
    #pragma unroll
    for (int o = 32; o; o >>= 1) lss += __shfl_xor(lss, o);
    if (lane == 0) red[wave] = lss;
    __syncthreads();
    if (tid == 0) {
        double vsum = 0.0;
        #pragma unroll
        for (int w = 0; w < 16; ++w) vsum += red[w];
        double stdv = sqrt(vsum / (double)(NC - 1));
        stdv = fmin(fmax(stdv, 1e-9), 1e9);
        out[0] = (float)((double)BATCH * stdv);
    }
}

// ---------------------------------------------------------------------------
extern "C" void kernel_launch(void* const* d_in, const int* in_sizes, int n_in,
                              void* d_out, int out_size, void* d_ws, size_t ws_size,
                              hipStream_t stream)
{
    (void)in_sizes; (void)n_in; (void)out_size; (void)ws_size;
    const float* seg  = (const float*)d_in[0];
    const float* Wq   = (const float*)d_in[1];
    const float* bq   = (const float*)d_in[2];
    const float* Wk   = (const float*)d_in[3];
    const float* bk   = (const float*)d_in[4];
    const float* Wv   = (const float*)d_in[5];
    const float* bv   = (const float*)d_in[6];
    const float* Wc   = (const float*)d_in[7];
    const float* bc   = (const float*)d_in[8];
    const float* ln_a = (const float*)d_in[9];
    const float* ln_b = (const float*)d_in[10];

    float* out = (float*)d_out;
    float* vid_probs = out;                           // 64*3862
    float* attn_idc  = out + (size_t)BATCH * NC;      // 64*3862
    float* scores    = attn_idc + (size_t)BATCH * NC; // 64*300*4
    float* attnw     = scores + (size_t)BATCH * SEQ * NH;
    float* convl     = attnw + (size_t)BATCH * SEQ * NH;

    char* wsp = (char*)d_ws;
    float*  QKV    = (float*)wsp;                              // 19200*768 f32 (59.0 MB)
    wsp += (size_t)MROWS * NSTK * sizeof(float);
    double* logits = (double*)wsp;                             // 256*3862 f64 (7.9 MB)
    wsp += (size_t)BATCH * NH * NC * sizeof(double);
    double* stats  = (double*)wsp;                             // 256*2 f64

    dim3 g1(MROWS / BM, NSTK / BN);   // (150, 6)
    proj_gemm_mfma<<<g1, 256, 0, stream>>>(seg, Wk, bk, Wv, bv, Wq, bq, QKV);

    attn_logits_kernel<<<BATCH * NH, 512, 0, stream>>>(
        QKV, Wc, bc, scores, attnw, logits, stats);

    dim3 g3((NC + 255) / 256, BATCH);
    finalize_kernel<<<g3, 256, 0, stream>>>(logits, stats, ln_a, ln_b, vid_probs, attn_idc);

    convloss_kernel<<<1, 1024, 0, stream>>>(Wc, bc, convl);
}

// Round 11
// 811.634 us; speedup vs baseline: 2.5963x; 2.5963x over previous
//
#include <hip/hip_runtime.h>
#include <math.h>

#define BATCH 64
#define SEQ 300
#define DM 1024
#define DP 128
#define NH 4
#define NC 3862
#define MROWS (BATCH*SEQ)   // 19200
#define NSTK (6*DP)         // 768: [K | V | Q0..Q3]

#define BM 128
#define BN 128
#define BK 16

typedef double d4 __attribute__((ext_vector_type(4)));

// ---------------------------------------------------------------------------
// Kernel 1: fused QKV projection GEMM on the f64 MFMA pipe.
// EXACT r9 PASS configuration (541 us, MfmaUtil 75%): launch_bounds(256,2).
// r10 lesson: (256,4) caps VGPR at 64 < 128-reg accumulator -> scratch spill
// (4.6 GB writes, 3.5x slowdown). 2 blocks/CU is the register ceiling:
// 2 waves/SIMD x ~212 regs = 424 <= 512; 3 waves would need 636.
// f64 MFMA layouts (HW-confirmed): A: i=lane&15, k=lane>>4;
// B: j=lane&15, k=lane>>4; D: row=(lane>>4)+4*reg, col=lane&15.
// XOR-swizzled staging (r9): granule kq' = kq ^ ((row>>2)&3) on BOTH the
// global source and the LDS read -> bank conflicts 1.03e8 -> 1.47e7.
// ---------------------------------------------------------------------------
__global__ __launch_bounds__(256, 2) void proj_gemm_mfma(
    const float* __restrict__ X,
    const float* __restrict__ Wk, const float* __restrict__ bk,
    const float* __restrict__ Wv, const float* __restrict__ bv,
    const float* __restrict__ Wq, const float* __restrict__ bq,
    float* __restrict__ O)
{
    const int mtile = blockIdx.x;   // 0..149
    const int wsel  = blockIdx.y;   // 0..5 : K,V,Q0..Q3

    const float* Wbase; const float* bias;
    if (wsel == 0)      { Wbase = Wk; bias = bk; }
    else if (wsel == 1) { Wbase = Wv; bias = bv; }
    else                { Wbase = Wq + (size_t)(wsel - 2) * DP * DM;
                          bias  = bq + (wsel - 2) * DP; }

    // [row][k] tiles; slot s holds global granule (row=s>>2, kq=(s&3)^((row>>2)&3))
    __shared__ float As[2][BM * BK];
    __shared__ float Bs[2][BN * BK];

    const int tid  = threadIdx.x;
    const int lane = tid & 63;
    const int wave = tid >> 6;
    const int wm = wave >> 1, wn = wave & 1;   // 2x2 wave grid
    const int mbase = mtile * BM;

    const int r = lane & 15;   // A row / B col / D col within 16-tile
    const int g = lane >> 4;   // k-subindex (0..3) for A/B; D row base
    const int sw = (r >> 2) & 3;   // per-lane XOR swizzle key

    d4 acc[4][4];
    #pragma unroll
    for (int mt = 0; mt < 4; ++mt)
        #pragma unroll
        for (int nt = 0; nt < 4; ++nt)
            acc[mt][nt] = (d4)(0.0);

#define STAGE(bufi, k0)                                                        \
    do {                                                                       \
        _Pragma("unroll")                                                      \
        for (int j = 0; j < 2; ++j) {                                          \
            const int slotbase = wave * 128 + j * 64;   /* wave-uniform */     \
            const int slot = slotbase + lane;                                  \
            const int mrow = slot >> 2;                                        \
            const int kq4  = (((slot & 3) ^ ((mrow >> 2) & 3))) << 2;          \
            const float* srcA = &X[(size_t)(mbase + mrow) * DM + (k0) + kq4];  \
            __builtin_amdgcn_global_load_lds(                                  \
                (const __attribute__((address_space(1))) void*)srcA,           \
                (__attribute__((address_space(3))) void*)&As[bufi][slotbase * 4], \
                16, 0, 0);                                                     \
            const float* srcB = &Wbase[(size_t)mrow * DM + (k0) + kq4];        \
            __builtin_amdgcn_global_load_lds(                                  \
                (const __attribute__((address_space(1))) void*)srcB,           \
                (__attribute__((address_space(3))) void*)&Bs[bufi][slotbase * 4], \
                16, 0, 0);                                                     \
        }                                                                      \
    } while (0)

    STAGE(0, 0);
    __syncthreads();   // drains vmcnt -> buf0 ready

    int buf = 0;
    for (int t = 0; t < DM / BK; ++t) {
        if (t + 1 < DM / BK) {
            if (buf == 0) STAGE(1, (t + 1) * BK);
            else          STAGE(0, (t + 1) * BK);
        }
        #pragma unroll
        for (int kq = 0; kq < 4; ++kq) {
            const int kqs = ((kq ^ sw) << 2) + g;
            double a[4], b[4];
            #pragma unroll
            for (int mt = 0; mt < 4; ++mt)
                a[mt] = (double)As[buf][(wm * 64 + mt * 16 + r) * BK + kqs];
            #pragma unroll
            for (int nt = 0; nt < 4; ++nt)
                b[nt] = (double)Bs[buf][(wn * 64 + nt * 16 + r) * BK + kqs];
            #pragma unroll
            for (int mt = 0; mt < 4; ++mt)
                #pragma unroll
                for (int nt = 0; nt < 4; ++nt)
                    acc[mt][nt] = __builtin_amdgcn_mfma_f64_16x16x4f64(
                        a[mt], b[nt], acc[mt][nt], 0, 0, 0);
        }
        __syncthreads();
        buf ^= 1;
    }
#undef STAGE

    // epilogue: D[row = g + 4*i][col = r] per 16x16 tile (f64 reg-strided)
    #pragma unroll
    for (int nt = 0; nt < 4; ++nt) {
        const int col = wn * 64 + nt * 16 + r;
        const double bi = (double)bias[col];
        #pragma unroll
        for (int mt = 0; mt < 4; ++mt) {
            #pragma unroll
            for (int i = 0; i < 4; ++i) {
                const int row = wm * 64 + mt * 16 + g + 4 * i;
                O[(size_t)(mbase + row) * NSTK + wsel * DP + col] =
                    (float)(acc[mt][nt][i] + bi);
            }
        }
    }
}

// ---------------------------------------------------------------------------
// Kernel 2: merged attention + logits GEMV + LN stats, per (b,h).
// 512 threads. Scores: 16-lane groups (4-level shuffle). ws kept in LDS
// (no global roundtrip). All reduction math f64 (argmax safety).
// ---------------------------------------------------------------------------
__global__ __launch_bounds__(512) void attn_logits_kernel(
    const float* __restrict__ QKV,
    const float* __restrict__ Wc, const float* __restrict__ bc,
    float* __restrict__ scores_out,  // [B][S][H] f32
    float* __restrict__ attnw_out,   // [B][S][H] f32
    double* __restrict__ logits,     // [BH][NC] f64
    double* __restrict__ stats)      // [BH][2]  f64
{
    const int b = blockIdx.x >> 2;
    const int h = blockIdx.x & 3;
    const int bh = blockIdx.x;
    const int tid = threadIdx.x;
    const int wave = tid >> 6, lane = tid & 63;

    __shared__ double sc[SEQ];
    __shared__ double red[8];
    __shared__ double wacc[4][DP];
    __shared__ double wsLDS[DP];

    const double scale = 0.08838834764831843;  // 1/sqrt(128)
    const float* base = QKV + (size_t)b * SEQ * NSTK;

    // ---- Phase A: scores. One 16-lane group per s (8 dims/lane).
    {
        const int grp = tid >> 4;   // 0..31
        const int l16 = tid & 15;
        for (int s = grp; s < SEQ; s += 32) {
            const float* row = base + (size_t)s * NSTK;
            const float4 q0 = *reinterpret_cast<const float4*>(row + 256 + h * DP + l16 * 8);
            const float4 q1 = *reinterpret_cast<const float4*>(row + 256 + h * DP + l16 * 8 + 4);
            const float4 k0 = *reinterpret_cast<const float4*>(row + l16 * 8);
            const float4 k1 = *reinterpret_cast<const float4*>(row + l16 * 8 + 4);
            double p = (double)q0.x * (double)k0.x + (double)q0.y * (double)k0.y
                     + (double)q0.z * (double)k0.z + (double)q0.w * (double)k0.w
                     + (double)q1.x * (double)k1.x + (double)q1.y * (double)k1.y
                     + (double)q1.z * (double)k1.z + (double)q1.w * (double)k1.w;
            p += __shfl_xor(p, 1);
            p += __shfl_xor(p, 2);
            p += __shfl_xor(p, 4);
            p += __shfl_xor(p, 8);
            p *= scale;
            if (l16 == 0) {
                sc[s] = p;
                scores_out[((size_t)b * SEQ + s) * NH + h] = (float)p;
            }
        }
    }
    __syncthreads();

    // ---- Phase B: softmax over SEQ (f64)
    double mx = -1e300;
    for (int i = tid; i < SEQ; i += 512) mx = fmax(mx, sc[i]);
    #pragma unroll
    for (int o = 32; o; o >>= 1) mx = fmax(mx, __shfl_xor(mx, o));
    if (lane == 0) red[wave] = mx;
    __syncthreads();
    mx = red[0];
    #pragma unroll
    for (int w = 1; w < 8; ++w) mx = fmax(mx, red[w]);
    __syncthreads();

    double lsum = 0.0;
    for (int i = tid; i < SEQ; i += 512) {
        const double e = exp(sc[i] - mx);
        sc[i] = e;
        lsum += e;
    }
    #pragma unroll
    for (int o = 32; o; o >>= 1) lsum += __shfl_xor(lsum, o);
    if (lane == 0) red[wave] = lsum;
    __syncthreads();
    double tot = 0.0;
    #pragma unroll
    for (int w = 0; w < 8; ++w) tot += red[w];
    const double inv = 1.0 / tot;
    __syncthreads();
    for (int i = tid; i < SEQ; i += 512) {
        const double p = sc[i] * inv;
        sc[i] = p;
        attnw_out[((size_t)b * SEQ + i) * NH + h] = (float)p;
    }
    __syncthreads();

    // ---- Phase C: ws[p] = sum_s p_attn[s] * vals[s][p]; 4 s-partials
    {
        const int p_idx = tid & 127, qtr = tid >> 7;
        double acc = 0.0;
        for (int s = qtr; s < SEQ; s += 4)
            acc = fma(sc[s], (double)base[(size_t)s * NSTK + 128 + p_idx], acc);
        wacc[qtr][p_idx] = acc;
    }
    __syncthreads();
    if (tid < DP) {
        const double w = wacc[0][tid] + wacc[1][tid] + wacc[2][tid] + wacc[3][tid];
        wsLDS[tid] = fmax(w, 0.0);   // relu
    }
    __syncthreads();

    // ---- Phase D: logits GEMV + LN stats
    double vals[8];
    int cnt = 0;
    double psum = 0.0;
    for (int c = tid; c < NC; c += 512) {
        const float4* wr = reinterpret_cast<const float4*>(Wc + (size_t)c * DP);
        double acc = 0.0;
        #pragma unroll
        for (int k = 0; k < 32; ++k) {
            const float4 v = wr[k];
            acc = fma((double)v.x, wsLDS[4 * k + 0], acc);
            acc = fma((double)v.y, wsLDS[4 * k + 1], acc);
            acc = fma((double)v.z, wsLDS[4 * k + 2], acc);
            acc = fma((double)v.w, wsLDS[4 * k + 3], acc);
        }
        acc += (double)bc[c];
        logits[(size_t)bh * NC + c] = acc;
        vals[cnt++] = acc;
        psum += acc;
    }
    #pragma unroll
    for (int o = 32; o; o >>= 1) psum += __shfl_xor(psum, o);
    if (lane == 0) red[wave] = psum;
    __syncthreads();
    double msum = 0.0;
    #pragma unroll
    for (int w = 0; w < 8; ++w) msum += red[w];
    const double mean = msum / (double)NC;
    __syncthreads();

    double lss = 0.0;
    for (int i = 0; i < cnt; ++i) {
        const double d = vals[i] - mean;
        lss = fma(d, d, lss);
    }
    #pragma unroll
    for (int o = 32; o; o >>= 1) lss += __shfl_xor(lss, o);
    if (lane == 0) red[wave] = lss;
    __syncthreads();
    if (tid == 0) {
        double vsum = 0.0;
        #pragma unroll
        for (int w = 0; w < 8; ++w) vsum += red[w];
        stats[bh * 2 + 0] = mean;
        stats[bh * 2 + 1] = sqrt(vsum / (double)(NC - 1));
    }
}

// ---------------------------------------------------------------------------
// Kernel 3: LN + max/argmax over heads + sigmoid, f64 compare path.
// ---------------------------------------------------------------------------
__global__ __launch_bounds__(256) void finalize_kernel(
    const double* __restrict__ logits, const double* __restrict__ stats,
    const float* __restrict__ ln_a, const float* __restrict__ ln_b,
    float* __restrict__ vid_probs, float* __restrict__ attn_idc)
{
    const int c = blockIdx.x * 256 + threadIdx.x;
    const int b = blockIdx.y;
    if (c >= NC) return;
    const double a = (double)ln_a[c], bb = (double)ln_b[c];
    double best = -1e300;
    int bi = 0;
    #pragma unroll
    for (int h = 0; h < NH; ++h) {
        const int bh = b * NH + h;
        const double x = logits[(size_t)bh * NC + c];
        const double ln = a * (x - stats[bh * 2]) / (stats[bh * 2 + 1] + 1e-6) + bb;
        if (ln > best) { best = ln; bi = h; }
    }
    vid_probs[(size_t)b * NC + c] = (float)(1.0 / (1.0 + exp(-best)));
    attn_idc[(size_t)b * NC + c] = (float)bi;
}

// ---------------------------------------------------------------------------
// Kernel 4: conv regularizer loss (Wc, bc only), f64. One block, 1024 thr.
// ---------------------------------------------------------------------------
__global__ __launch_bounds__(1024) void convloss_kernel(
    const float* __restrict__ Wc, const float* __restrict__ bc,
    float* __restrict__ out)
{
    __shared__ double t[NC];
    __shared__ double red[16];
    const int tid = threadIdx.x;
    const int wave = tid >> 6, lane = tid & 63;

    double lmax = -1e300;
    for (int c = tid; c < NC; c += 1024) {
        const float4* wr = reinterpret_cast<const float4*>(Wc + (size_t)c * DP);
        double acc = 0.0;
        #pragma unroll
        for (int k = 0; k < 32; ++k) {
            const float4 v = wr[k];
            acc += (double)v.x + (double)v.y + (double)v.z + (double)v.w;
        }
        acc += (double)bc[c];
        t[c] = acc;
        lmax = fmax(lmax, acc);
    }
    #pragma unroll
    for (int o = 32; o; o >>= 1) lmax = fmax(lmax, __shfl_xor(lmax, o));
    if (lane == 0) red[wave] = lmax;
    __syncthreads();
    double mx = red[0];
    #pragma unroll
    for (int w = 1; w < 16; ++w) mx = fmax(mx, red[w]);
    __syncthreads();

    double lsum = 0.0;
    for (int c = tid; c < NC; c += 1024) {
        const double e = exp(t[c] - mx);
        t[c] = e;
        lsum += e;
    }
    #pragma unroll
    for (int o = 32; o; o >>= 1) lsum += __shfl_xor(lsum, o);
    if (lane == 0) red[wave] = lsum;
    __syncthreads();
    double tot = 0.0;
    #pragma unroll
    for (int w = 0; w < 16; ++w) tot += red[w];
    const double inv = 1.0 / tot;
    __syncthreads();

    double psum = 0.0;
    for (int c = tid; c < NC; c += 1024) {
        const double p = t[c] * inv;
        t[c] = p;
        psum += p;
    }
    #pragma unroll
    for (int o = 32; o; o >>= 1) psum += __shfl_xor(psum, o);
    if (lane == 0) red[wave] = psum;
    __syncthreads();
    double msum = 0.0;
    #pragma unroll
    for (int w = 0; w < 16; ++w) msum += red[w];
    const double mean = msum / (double)NC;
    __syncthreads();

    double lss = 0.0;
    for (int c = tid; c < NC; c += 1024) {
        const double d = t[c] - mean;
        lss = fma(d, d, lss);
    }
    #pragma unroll
    for (int o = 32; o; o >>= 1) lss += __shfl_xor(lss, o);
    if (lane == 0) red[wave] = lss;
    __syncthreads();
    if (tid == 0) {
        double vsum = 0.0;
        #pragma unroll
        for (int w = 0; w < 16; ++w) vsum += red[w];
        double stdv = sqrt(vsum / (double)(NC - 1));
        stdv = fmin(fmax(stdv, 1e-9), 1e9);
        out[0] = (float)((double)BATCH * stdv);
    }
}

// ---------------------------------------------------------------------------
extern "C" void kernel_launch(void* const* d_in, const int* in_sizes, int n_in,
                              void* d_out, int out_size, void* d_ws, size_t ws_size,
                              hipStream_t stream)
{
    (void)in_sizes; (void)n_in; (void)out_size; (void)ws_size;
    const float* seg  = (const float*)d_in[0];
    const float* Wq   = (const float*)d_in[1];
    const float* bq   = (const float*)d_in[2];
    const float* Wk   = (const float*)d_in[3];
    const float* bk   = (const float*)d_in[4];
    const float* Wv   = (const float*)d_in[5];
    const float* bv   = (const float*)d_in[6];
    const float* Wc   = (const float*)d_in[7];
    const float* bc   = (const float*)d_in[8];
    const float* ln_a = (const float*)d_in[9];
    const float* ln_b = (const float*)d_in[10];

    float* out = (float*)d_out;
    float* vid_probs = out;                           // 64*3862
    float* attn_idc  = out + (size_t)BATCH * NC;      // 64*3862
    float* scores    = attn_idc + (size_t)BATCH * NC; // 64*300*4
    float* attnw     = scores + (size_t)BATCH * SEQ * NH;
    float* convl     = attnw + (size_t)BATCH * SEQ * NH;

    char* wsp = (char*)d_ws;
    float*  QKV    = (float*)wsp;                              // 19200*768 f32 (59.0 MB)
    wsp += (size_t)MROWS * NSTK * sizeof(float);
    double* logits = (double*)wsp;                             // 256*3862 f64 (7.9 MB)
    wsp += (size_t)BATCH * NH * NC * sizeof(double);
    double* stats  = (double*)wsp;                             // 256*2 f64

    dim3 g1(MROWS / BM, NSTK / BN);   // (150, 6)
    proj_gemm_mfma<<<g1, 256, 0, stream>>>(seg, Wk, bk, Wv, bv, Wq, bq, QKV);

    attn_logits_kernel<<<BATCH * NH, 512, 0, stream>>>(
        QKV, Wc, bc, scores, attnw, logits, stats);

    dim3 g3((NC + 255) / 256, BATCH);
    finalize_kernel<<<g3, 256, 0, stream>>>(logits, stats, ln_a, ln_b, vid_probs, attn_idc);

    convloss_kernel<<<1, 1024, 0, stream>>>(Wc, bc, convl);
}